// Round 4
// baseline (1295.274 us; speedup 1.0000x reference)
//
#include <hip/hip_runtime.h>
#include <math.h>

// HebbyRNN: B=32, IN=128, H=1024, OUT=128
// R5: single fused kernel with HAND-ROLLED grid barrier (plain launch).
//   R4's hipLaunchCooperativeKernel silently no-opped under the harness's graph
//   capture (absmax 5.31 == log_softmax-of-zeros signature: kernel never ran).
//   - 1024 blocks x 256 thr, __launch_bounds__(256,4) -> 4 blocks/CU guaranteed
//     -> all 1024 blocks co-resident -> spin barrier is deadlock-free.
//   - barrier counters in d_ws[0..15], zeroed via hipMemsetAsync each launch
//     (graph-capture-legal; robust to workspace re-poisoning).
//   - device-scope atomics + __threadfence() both sides: correct across
//     non-coherent per-XCD L2s and across graph replays (stale-line inval).
//   - 8 rows/wave per layer (4096 waves x 8 = 32768 = B*H rows).
//   - heads: 8 Wh rows + exactly 1 Wo row per wave; logsoftmax on waves 0..31.

#define B_SZ 32
#define IN_SZ 128
#define H_SZ 1024
#define OUT_SZ 128
#define NBLOCK 1024

typedef float f4 __attribute__((ext_vector_type(4)));

__device__ __forceinline__ float dot4(f4 w, f4 a, float acc) {
    acc = fmaf(w.x, a.x, acc);
    acc = fmaf(w.y, a.y, acc);
    acc = fmaf(w.z, a.z, acc);
    acc = fmaf(w.w, a.w, acc);
    return acc;
}

// Full 64-lane butterfly: every lane ends with the total.
__device__ __forceinline__ float wave_allreduce(float s) {
    #pragma unroll
    for (int off = 32; off > 0; off >>= 1)
        s += __shfl_xor(s, off, 64);
    return s;
}

// lane in [0,8): pick acc[lane] without dynamic register indexing.
__device__ __forceinline__ float sel8(const float acc[8], int lane) {
    float v = acc[0];
    v = (lane == 1) ? acc[1] : v;
    v = (lane == 2) ? acc[2] : v;
    v = (lane == 3) ? acc[3] : v;
    v = (lane == 4) ? acc[4] : v;
    v = (lane == 5) ? acc[5] : v;
    v = (lane == 6) ? acc[6] : v;
    v = (lane == 7) ? acc[7] : v;
    return v;
}

// Grid-wide barrier: all NBLOCK blocks co-resident (guaranteed by launch bounds).
// Writer side: __threadfence() flushes this block's prior writes to the
// device-coherent point before signaling. Reader side: __threadfence() after
// the wait invalidates stale L1/L2 lines (cross-XCD + previous graph replay).
__device__ __forceinline__ void grid_barrier(unsigned* __restrict__ bar, int idx) {
    __syncthreads();
    if (threadIdx.x == 0) {
        __threadfence();
        atomicAdd(&bar[idx], 1u);
        while (__hip_atomic_load(&bar[idx], __ATOMIC_ACQUIRE,
                                 __HIP_MEMORY_SCOPE_AGENT) < (unsigned)NBLOCK) {
            __builtin_amdgcn_s_sleep(1);
        }
    }
    __syncthreads();
    __threadfence();
}

// One middle layer: 8 rows of W[b] (1024 wide) dotted with vin[b] -> tanh -> vout.
__device__ __forceinline__ void mid8(const float* __restrict__ W,
                                     const float* __restrict__ bias,
                                     const float* __restrict__ vin,
                                     float* __restrict__ vout,
                                     int w, int lane) {
    int r0 = w << 3;
    int b  = w >> 7;
    const f4* __restrict__ vr = (const f4*)(vin + b * H_SZ);
    f4 a[4];
    #pragma unroll
    for (int k = 0; k < 4; k++) a[k] = vr[lane + 64 * k];

    float acc[8];
    #pragma unroll
    for (int r = 0; r < 8; r++) {
        const f4* __restrict__ Wr = (const f4*)(W + (size_t)(r0 + r) * H_SZ);
        float s = 0.f;
        #pragma unroll
        for (int k = 0; k < 4; k++) s = dot4(Wr[lane + 64 * k], a[k], s);
        acc[r] = s;
    }
    #pragma unroll
    for (int r = 0; r < 8; r++) acc[r] = wave_allreduce(acc[r]);
    if (lane < 8) {
        float s = sel8(acc, lane);
        vout[r0 + lane] = tanhf(s + bias[(r0 & (H_SZ - 1)) + lane]);
    }
}

__global__ __launch_bounds__(256, 4) void fused_kernel(
        const float* __restrict__ x, const float* __restrict__ hidden,
        const float* __restrict__ W0, const float* __restrict__ b0,
        const float* __restrict__ W1, const float* __restrict__ b1,
        const float* __restrict__ W2, const float* __restrict__ b2,
        const float* __restrict__ Wh, const float* __restrict__ bh,
        const float* __restrict__ Wo, const float* __restrict__ bo,
        unsigned* __restrict__ bar,
        float* __restrict__ c1, float* __restrict__ c2,
        float* __restrict__ logits, float* __restrict__ out_ls,
        float* __restrict__ new_hidden) {
    const int w    = blockIdx.x * 4 + (threadIdx.x >> 6);   // 0..4095
    const int lane = threadIdx.x & 63;
    const int r0   = w << 3;                                // 8 rows/wave
    const int b    = w >> 7;                                // batch sample

    // ---- Layer 0: W0[b] (1024 x 1152) * concat(x[b],hidden[b]) -> tanh -> c1
    {
        const f4* __restrict__ x4 = (const f4*)(x + b * IN_SZ);       // 32 f4
        const f4* __restrict__ h4 = (const f4*)(hidden + b * H_SZ);   // 256 f4
        f4 a[4];
        #pragma unroll
        for (int k = 0; k < 4; k++) {
            int j = lane + 64 * k;
            a[k] = (j < 32) ? x4[j] : h4[j - 32];
        }
        f4 a4 = {0.f, 0.f, 0.f, 0.f};
        if (lane < 32) a4 = h4[224 + lane];

        float acc[8];
        #pragma unroll
        for (int r = 0; r < 8; r++) {
            const f4* __restrict__ Wr = (const f4*)(W0 + (size_t)(r0 + r) * (IN_SZ + H_SZ));
            float s = 0.f;
            #pragma unroll
            for (int k = 0; k < 4; k++) s = dot4(Wr[lane + 64 * k], a[k], s);
            if (lane < 32) s = dot4(Wr[256 + lane], a4, s);
            acc[r] = s;
        }
        #pragma unroll
        for (int r = 0; r < 8; r++) acc[r] = wave_allreduce(acc[r]);
        if (lane < 8) {
            float s = sel8(acc, lane);
            c1[r0 + lane] = tanhf(s + b0[(r0 & (H_SZ - 1)) + lane]);
        }
    }
    grid_barrier(bar, 0);

    // ---- Layer 1: c1 -> c2, Layer 2: c2 -> c1
    mid8(W1, b1, c1, c2, w, lane);
    grid_barrier(bar, 1);
    mid8(W2, b2, c2, c1, w, lane);
    grid_barrier(bar, 2);

    // ---- Heads: 8 Wh rows (tanh -> new_hidden) + 1 Wo row (-> logits) per wave
    {
        const f4* __restrict__ vr = (const f4*)(c1 + b * H_SZ);
        f4 a[4];
        #pragma unroll
        for (int k = 0; k < 4; k++) a[k] = vr[lane + 64 * k];

        float acc[8];
        #pragma unroll
        for (int r = 0; r < 8; r++) {
            const f4* __restrict__ Wr = (const f4*)(Wh + (size_t)(r0 + r) * H_SZ);
            float s = 0.f;
            #pragma unroll
            for (int k = 0; k < 4; k++) s = dot4(Wr[lane + 64 * k], a[k], s);
            acc[r] = s;
        }
        const f4* __restrict__ Wor = (const f4*)(Wo + (size_t)w * H_SZ);
        float so = 0.f;
        #pragma unroll
        for (int k = 0; k < 4; k++) so = dot4(Wor[lane + 64 * k], a[k], so);

        #pragma unroll
        for (int r = 0; r < 8; r++) acc[r] = wave_allreduce(acc[r]);
        so = wave_allreduce(so);

        if (lane < 8) {
            float s = sel8(acc, lane);
            new_hidden[r0 + lane] = tanhf(s + bh[(r0 & (H_SZ - 1)) + lane]);
        }
        if (lane == 8) {
            logits[w] = so + bo[w & (OUT_SZ - 1)];   // (w>>7)*128 + (w&127) = w
        }
    }
    grid_barrier(bar, 3);

    // ---- log_softmax over OUT=128, waves 0..31 (one wave per batch row)
    if (w < B_SZ) {
        float v0 = logits[w * OUT_SZ + lane];
        float v1 = logits[w * OUT_SZ + 64 + lane];
        float m = fmaxf(v0, v1);
        #pragma unroll
        for (int off = 32; off > 0; off >>= 1)
            m = fmaxf(m, __shfl_xor(m, off, 64));
        float e = __expf(v0 - m) + __expf(v1 - m);
        #pragma unroll
        for (int off = 32; off > 0; off >>= 1)
            e += __shfl_xor(e, off, 64);
        float lse = m + logf(e);
        out_ls[w * OUT_SZ + lane]      = v0 - lse;
        out_ls[w * OUT_SZ + 64 + lane] = v1 - lse;
    }
}

extern "C" void kernel_launch(void* const* d_in, const int* in_sizes, int n_in,
                              void* d_out, int out_size, void* d_ws, size_t ws_size,
                              hipStream_t stream) {
    const float* x      = (const float*)d_in[0];
    const float* hidden = (const float*)d_in[1];
    const float* W0 = (const float*)d_in[2];
    const float* b0 = (const float*)d_in[3];
    const float* W1 = (const float*)d_in[4];
    const float* b1 = (const float*)d_in[5];
    const float* W2 = (const float*)d_in[6];
    const float* b2 = (const float*)d_in[7];
    const float* Wh = (const float*)d_in[8];
    const float* bh = (const float*)d_in[9];
    const float* Wo = (const float*)d_in[10];
    const float* bo = (const float*)d_in[11];

    float* out_ls     = (float*)d_out;              // [32,128] log_softmax
    float* new_hidden = out_ls + B_SZ * OUT_SZ;     // [32,1024]

    float* wsf = (float*)d_ws;
    unsigned* bar = (unsigned*)wsf;                  // 16 counters (use 4)
    float* c1 = wsf + 64;                            // 32*1024
    float* c2 = c1 + B_SZ * H_SZ;                    // 32*1024
    float* logits = c2 + B_SZ * H_SZ;                // 32*128

    // Zero the barrier counters (graph-capture-legal stream op).
    hipMemsetAsync(d_ws, 0, 64, stream);

    fused_kernel<<<NBLOCK, 256, 0, stream>>>(
        x, hidden, W0, b0, W1, b1, W2, b2, Wh, bh, Wo, bo,
        bar, c1, c2, logits, out_ls, new_hidden);
}